// Round 11
// baseline (212.339 us; speedup 1.0000x reference)
//
#include <hip/hip_runtime.h>

#define NB 32768
#define MAXTILE 768
#define ROWS 64
#define NT 4
#define XHS 536            // xh stride in u16: 268 dw ≡ 12 mod 32 → phase-minimal LDS access

typedef short s8v __attribute__((ext_vector_type(8)));   // 8 x bf16 bits (4 VGPR)
typedef short s4v __attribute__((ext_vector_type(4)));
typedef float f4v __attribute__((ext_vector_type(4)));
typedef unsigned short u16;
typedef unsigned short u16x4 __attribute__((ext_vector_type(4)));
typedef unsigned int u32;
typedef unsigned char u8;

__device__ __forceinline__ float bf2f(u16 u) { return __uint_as_float(((u32)u) << 16); }
__device__ __forceinline__ u16 f2bf(float f) {
    u32 x = __float_as_uint(f);
    x += 0x7FFFu + ((x >> 16) & 1u);   // RNE
    return (u16)(x >> 16);
}
__device__ __forceinline__ s8v ld8(const u16* p) { return *reinterpret_cast<const s8v*>(p); }

#define MFMA16(a, b, c) __builtin_amdgcn_mfma_f32_16x16x32_bf16((a), (b), (c), 0, 0, 0)

template <int N> struct IC { static constexpr int v = N; };

// dtype probe, done locally per block (wave 0 ballot -> LDS). bf16=1, f32=0.
__device__ __forceinline__ void detect_flag(const void* input, int tid, int* shflag)
{
    if (tid < 64) {
        u32 w = ((const u32*)input)[tid];
        u32 h0 = w & 0xFFFFu;
        u32 e0 = (h0 >> 7) & 0xFFu;
        bool plaus = (h0 == 0u) || (e0 >= 96u && e0 <= 143u);
        unsigned long long m = __ballot(plaus);
        if (tid == 0) *shflag = (__popcll(m) >= 48) ? 1 : 0;
    }
}

// ---------------------------------------------------------------------------
// dispatch A: blocks [0,128): per-block key histogram -> histT[key][block]
// (transposed for scatter coalescing) + keyloc[row] = key | (rank<<8).
// blocks [128,1093): weight repack in FINE units (2048 elems, 4KB LDS tile)
// + bias conversion. High block count -> latency hiding by occupancy.
// ---------------------------------------------------------------------------
struct RepArgs {
    const void* W01; const void* Wp[3]; const void* pre[4]; const void* fin;
    const void* bias[9];
    u16 *rPre, *rW01, *rWp[3], *rFin, *cbias;
};

__global__ __launch_bounds__(256) void prepA_kernel(const void* __restrict__ inputv,
                                                    int* __restrict__ histT,      // [256][128]
                                                    u16* __restrict__ keyloc,     // [NB]
                                                    RepArgs R)
{
    __shared__ int lcnt[256];
    __shared__ u16 T[2048];
    __shared__ int shmisc;
    int tid = threadIdx.x;
    int b = blockIdx.x;
    detect_flag(inputv, tid, &shmisc);
    __syncthreads();
    int flag = shmisc;

    if (b < 128) {
        lcnt[tid] = 0;
        __syncthreads();
        int row = (b << 8) + tid;
        const u32* in32 = (const u32*)inputv;
        const u16* in16 = (const u16*)inputv;
        int key = 0;
#pragma unroll
        for (int j = 0; j < 4; j++) {
            int base = row * 144 + 128 + j * 4;
            u32 v1, v2, v3;
            if (flag) { v1 = in16[base + 1]; v2 = in16[base + 2]; v3 = in16[base + 3]; }
            else      { v1 = in32[base + 1]; v2 = in32[base + 2]; v3 = in32[base + 3]; }
            int m = v1 ? 1 : (v2 ? 2 : (v3 ? 3 : 0));
            key |= m << (j << 1);
        }
        int loc = atomicAdd(&lcnt[key], 1);
        keyloc[row] = (u16)(key | (loc << 8));
        __syncthreads();
        histT[tid * 128 + b] = lcnt[tid];
        return;
    }

    // ---- repack path: fine units
    int rb = b - 128;
    const void* src; u16* dst; int K, k0, mrow, kq;
    if (rb < 128) {
        int tile = rb >> 2; kq = rb & 3;
        int m = tile >> 3, s = tile & 7;
        src = R.W01; dst = R.rW01 + (m * 8 + s) * 8192; K = 256; k0 = s * 32; mrow = m;
    } else if (rb < 896) {
        int u = rb - 128, mat = u >> 8, r = u & 255;
        int tile = r >> 2; kq = r & 3;
        int m = tile >> 4, s = tile & 15;
        src = R.Wp[mat]; dst = R.rWp[mat] + (m * 16 + s) * 8192; K = 512; k0 = s * 32; mrow = m;
    } else if (rb < 960) {
        int u = rb - 896;
        int tile = u >> 2; kq = u & 3;
        int mat = tile >> 2, m = tile & 3;
        src = R.pre[mat]; dst = R.rPre + (mat * 4 + m) * 8192; K = 32; k0 = 0; mrow = m;
    } else if (rb < 964) {
        int m = rb - 960;   // Wfin [m][256][8] -> [m][s8][lane][8], rows l16>=8 zero
        const u16* s16 = (const u16*)R.fin;
        const float* s32 = (const float*)R.fin;
        // process in 2 halves of 1024 src elems to fit T[2048]
        u16* d = R.rFin + m * 4096;
        for (int half = 0; half < 2; half++) {
            for (int i = tid; i < 1024; i += 256) {
                int kk = half * 128 + (i >> 3);
                T[i] = flag ? s16[(m * 256 + kk) * 8 + (i & 7)]
                            : f2bf(s32[(m * 256 + kk) * 8 + (i & 7)]);
            }
            __syncthreads();
            // dst slices s in [half*4, half*4+4)
            for (int i = tid; i < 2048; i += 256) {
                int s = (half << 2) + (i >> 9), lane = (i >> 3) & 63, j = i & 7;
                int q = lane >> 4, l16 = lane & 15;
                int k = s * 32 + q * 8 + j;           // absolute k in [half*128, ...)
                d[s * 512 + lane * 8 + j] = (l16 < 8) ? T[(k - half * 128) * 8 + l16] : (u16)0;
            }
            __syncthreads();
        }
        return;
    } else {
        const int sz[9] = {1024,1024,1024,1024,1024,1024,1024,1024,32};
        const int of[9] = {0,1024,2048,3072,4096,5120,6144,7168,8192};
        for (int i = tid; i < 8224; i += 256) {
            int t = i, e = 0;
            while (t >= sz[e]) { t -= sz[e]; e++; }
            R.cbias[of[e] + t] = flag ? ((const u16*)R.bias[e])[t]
                                      : f2bf(((const float*)R.bias[e])[t]);
        }
        return;
    }
    const u16* s16 = (const u16*)src;
    const float* s32 = (const float*)src;
    // load 8 k-rows x 256 n (coalesced)
    for (int i = tid; i < 2048; i += 256) {
        int kk = i >> 8, n = i & 255;
        int srcIdx = (mrow * K + k0 + kq * 8 + kk) * 256 + n;
        T[i] = flag ? s16[srcIdx] : f2bf(s32[srcIdx]);
    }
    __syncthreads();
    // write quad kq of each mt-fragment: dst[mt*512 + kq*128 + r], r = l15*8+j
    for (int i = tid; i < 2048; i += 256) {
        int mt = i >> 7, r = i & 127, l15 = r >> 3, j = i & 7;
        dst[mt * 512 + kq * 128 + r] = T[j * 256 + mt * 16 + l15];
    }
}

// ---------------------------------------------------------------------------
// dispatch B: 128 blocks. Redundant per-block scan (no spin): thread=key reads
// its transposed hist row (32 int4, unrolled, pipelined) -> base; LDS scan
// over keys; block 0 emits tile table; scatter perm.
// ---------------------------------------------------------------------------
__global__ __launch_bounds__(256) void scatter_kernel(const int* __restrict__ histT,
                                                      const u16* __restrict__ keyloc,
                                                      int* __restrict__ perm,
                                                      int4* __restrict__ tileInfo)
{
    __shared__ int lcnt[256];
    __shared__ int sBase[256];
    int tid = threadIdx.x;
    int b = blockIdx.x;

    const int4* hrow = (const int4*)(histT + tid * 128);
    int tot = 0, before = 0;
#pragma unroll
    for (int j = 0; j < 32; j++) {
        int4 h = hrow[j];
        int i4 = j << 2;
        tot += h.x + h.y + h.z + h.w;
        if (i4 + 0 < b) before += h.x;
        if (i4 + 1 < b) before += h.y;
        if (i4 + 2 < b) before += h.z;
        if (i4 + 3 < b) before += h.w;
    }
    lcnt[tid] = tot;
    __syncthreads();
    for (int off = 1; off < 256; off <<= 1) {
        int v = (tid >= off) ? lcnt[tid - off] : 0;
        __syncthreads();
        lcnt[tid] += v;
        __syncthreads();
    }
    int gbase = lcnt[tid] - tot;
    sBase[tid] = gbase + before;
    __syncthreads();

    if (b == 0) {
        int tiles = (tot + ROWS - 1) / ROWS;
        lcnt[tid] = tiles;
        __syncthreads();
        for (int off = 1; off < 256; off <<= 1) {
            int v = (tid >= off) ? lcnt[tid - off] : 0;
            __syncthreads();
            lcnt[tid] += v;
            __syncthreads();
        }
        int tbase = lcnt[tid] - tiles;
        int ttot = lcnt[255];
        for (int t = 0; t < tiles; t++) {
            int rem = tot - t * ROWS;
            tileInfo[tbase + t] = make_int4(tid, gbase + t * ROWS, rem > ROWS ? ROWS : rem, 0);
        }
        for (int i = ttot + tid; i < MAXTILE; i += 256)
            tileInfo[i] = make_int4(0, 0, 0, 0);
    }

    // ---- scatter perm
    int row = (b << 8) + tid;
    u32 kl = keyloc[row];
    int key = kl & 255, loc = kl >> 8;
    perm[sBase[key] + loc] = row;
}

// ---------------------------------------------------------------------------
// main: one block = 64 rows through the whole net (T-formulation).
// 1024 threads / 16 waves; wave w owns m-tile w (16 cols) x 4 n-tiles.
// Same weight-load intensity as the 512-thread/2-mt variant but 8 waves/SIMD
// (2 blocks/CU x 16 waves): double the latency-hiding TLP. VGPR capped 64.
// ---------------------------------------------------------------------------
struct MainP { const u16 *rPre, *rW01, *rWp1, *rWp2, *rWp3, *rFin, *cbias; };

__global__ __launch_bounds__(1024, 8) void main_kernel(
    const void* __restrict__ inRaw,
    const int* __restrict__ perm, const int4* __restrict__ tileInfo,
    MainP P, void* __restrict__ outp)
{
    __shared__ __align__(16) u16 xh[ROWS * XHS];
    __shared__ int rowids[ROWS];
    __shared__ int shflag;

    int tid = threadIdx.x;
    int lane = tid & 63, w = tid >> 6, quad = lane >> 4, l16 = lane & 15;

    int4 ti = tileInfo[blockIdx.x];
    int key = ti.x, ppos = ti.y, cntIn = ti.z;
    if (cntIn <= 0) return;

    detect_flag(inRaw, tid, &shflag);
    if (tid < ROWS) {
        int g = tid < cntIn ? tid : cntIn - 1;   // clamp partial tile (dups benign)
        rowids[tid] = perm[ppos + g];
    }
    __syncthreads();
    int flag = shflag;
    int rows_[NT];
#pragma unroll
    for (int nt = 0; nt < NT; nt++) rows_[nt] = rowids[nt * 16 + l16];

    const u16* in16 = (const u16*)inRaw;
    const float* in32 = (const float*)inRaw;
    int mt = w;

    f4v acc[NT];
    s8v fb[NT];

    // N-slice fused GEMM: depth-3 prefetch issued BEFORE the hp-visibility
    // barrier (A-frags don't depend on xh).
    auto gemm_run = [&](auto nc, const u16* Ab, int ks0) {
        constexpr int N = decltype(nc)::v;
        constexpr int D = 3;
        const u16* base = Ab + mt * 512 + lane * 8;
        s8v A[D];
#pragma unroll
        for (int d = 0; d < D && d < N; d++) A[d] = ld8(base + d * 8192);
        __syncthreads();                     // hp/hq now visible; prefetch in flight
#pragma unroll
        for (int s = 0; s < N; s++) {
            s8v c = A[s % D];
            if (s + D < N) A[s % D] = ld8(base + (s + D) * 8192);
#pragma unroll
            for (int nt = 0; nt < NT; nt++) {
                s8v B = ld8(&xh[(nt * 16 + l16) * XHS + (ks0 + s) * 32 + quad * 8]);
                acc[nt] = MFMA16(c, B, acc[nt]);
            }
        }
    };

    for (int node = 0; node < 4; node++) {
        int m = (key >> (node << 1)) & 3;

        // ---- feats B-frags (direct gather; TLP hides the latency)
#pragma unroll
        for (int nt = 0; nt < NT; nt++) {
            int off = rows_[nt] * 144 + (node << 5) + (quad << 3);
            if (flag) fb[nt] = ld8(in16 + off);
            else {
                f4v f0 = *(const f4v*)(in32 + off);
                f4v f1 = *(const f4v*)(in32 + off + 4);
                s8v r;
#pragma unroll
                for (int j = 0; j < 4; j++) { r[j] = (short)f2bf(f0[j]); r[4 + j] = (short)f2bf(f1[j]); }
                fb[nt] = r;
            }
        }

        // ---- hp^T = relu(Wpre^T @ feats^T + bpre) -> xh[.,256..511]
        {
            const u16* preB = P.rPre + ((node << 2) + m) * 8192;
            s8v a = ld8(preB + mt * 512 + lane * 8);
            u16x4 bv = *(const u16x4*)(P.cbias + node * 2048 + m * 256 + mt * 16 + quad * 4);
            f4v bias;
#pragma unroll
            for (int r = 0; r < 4; r++) bias[r] = bf2f(bv[r]);
#pragma unroll
            for (int nt = 0; nt < NT; nt++) {
                f4v c = MFMA16(a, fb[nt], bias);
                s4v p;
#pragma unroll
                for (int r = 0; r < 4; r++) { float v = c[r] > 0.f ? c[r] : 0.f; p[r] = (short)f2bf(v); }
                *(s4v*)&xh[(nt * 16 + l16) * XHS + 256 + mt * 16 + quad * 4] = p;
            }
        }

        // ---- acc init with bpost
        {
            u16x4 bv = *(const u16x4*)(P.cbias + node * 2048 + 1024 + m * 256 + mt * 16 + quad * 4);
            f4v f0;
#pragma unroll
            for (int r = 0; r < 4; r++) f0[r] = bf2f(bv[r]);
#pragma unroll
            for (int nt = 0; nt < NT; nt++) acc[nt] = f0;
        }

        // ---- fused K-loop (barrier inside gemm_run, after prefetch issue)
        if (node == 0) gemm_run(IC<8>{},  P.rW01 + m * 8 * 8192, 8);
        else {
            const u16* WB = (node == 1 ? P.rWp1 : (node == 2 ? P.rWp2 : P.rWp3)) + m * 16 * 8192;
            gemm_run(IC<16>{}, WB, 0);
        }
        __syncthreads();                       // all xh reads of this node done

        // ---- relu + write hq^T -> xh[.,0..255]
#pragma unroll
        for (int nt = 0; nt < NT; nt++) {
            s4v p;
#pragma unroll
            for (int r = 0; r < 4; r++) { float v = acc[nt][r] > 0.f ? acc[nt][r] : 0.f; p[r] = (short)f2bf(v); }
            *(s4v*)&xh[(nt * 16 + l16) * XHS + mt * 16 + quad * 4] = p;
        }
    }
    __syncthreads();

    // ---- final: out^T = Wfin^T @ x3^T + bfin (waves 0..NT-1 cover all rows)
    if (w < NT) {
        int m3 = (key >> 6) & 3;
        f4v c;
#pragma unroll
        for (int r = 0; r < 4; r++)
            c[r] = (quad < 2) ? bf2f(P.cbias[8192 + m3 * 8 + quad * 4 + r]) : 0.f;
#pragma unroll
        for (int s = 0; s < 8; s++) {
            s8v A = ld8(P.rFin + m3 * 4096 + s * 512 + lane * 8);
            s8v B = ld8(&xh[(w * 16 + l16) * XHS + s * 32 + quad * 8]);
            c = MFMA16(A, B, c);
        }
        int bidx = w * 16 + l16;
        if (quad < 2 && bidx < cntIn) {
            int row = rowids[bidx];
            if (flag) {
                s4v p;
#pragma unroll
                for (int r = 0; r < 4; r++) p[r] = (short)f2bf(c[r]);
                *(s4v*)((u16*)outp + row * 8 + quad * 4) = p;
            } else {
                *(f4v*)((float*)outp + row * 8 + quad * 4) = c;
            }
        }
    }
}

// ---------------------------------------------------------------------------
extern "C" void kernel_launch(void* const* d_in, const int* in_sizes, int n_in,
                              void* d_out, int out_size, void* d_ws, size_t ws_size,
                              hipStream_t stream)
{
    (void)in_sizes; (void)n_in; (void)out_size;
    const void* input  = d_in[0];
    const void* W00    = d_in[1];
    const void* b00    = d_in[2];
    const void* W01    = d_in[3];
    const void* b01    = d_in[4];
    const void* Wpre1  = d_in[5];
    const void* bpre1  = d_in[6];
    const void* Wpost1 = d_in[7];
    const void* bpost1 = d_in[8];
    const void* Wpre2  = d_in[9];
    const void* bpre2  = d_in[10];
    const void* Wpost2 = d_in[11];
    const void* bpost2 = d_in[12];
    const void* Wpre3  = d_in[13];
    const void* bpre3  = d_in[14];
    const void* Wpost3 = d_in[15];
    const void* bpost3 = d_in[16];
    const void* Wfin   = d_in[17];
    const void* bfin   = d_in[18];

    char* base = (char*)d_ws;
    size_t off = 0;
    auto alloc = [&](size_t bytes) -> char* {
        char* p = base + off;
        off += (bytes + 255) & ~(size_t)255;
        return p;
    };
    int*  histT     = (int*)alloc(256 * 128 * 4);     // [key][block]
    u16*  keyloc    = (u16*)alloc(NB * 2);
    int4* tileInfo  = (int4*)alloc(MAXTILE * 16);
    int*  perm      = (int*)alloc((size_t)NB * 4);
    u16*  cbias    = (u16*)alloc(8224 * 2);
    u16*  rPre     = (u16*)alloc(131072 * 2);
    u16*  rW01     = (u16*)alloc(262144 * 2);
    u16*  rWp1     = (u16*)alloc(524288 * 2);
    u16*  rWp2     = (u16*)alloc(524288 * 2);
    u16*  rWp3     = (u16*)alloc(524288 * 2);
    u16*  rFin     = (u16*)alloc(16384 * 2);
    if (off > ws_size) return;

    RepArgs R;
    R.W01 = W01; R.Wp[0] = Wpost1; R.Wp[1] = Wpost2; R.Wp[2] = Wpost3;
    R.pre[0] = W00; R.pre[1] = Wpre1; R.pre[2] = Wpre2; R.pre[3] = Wpre3;
    R.fin = Wfin;
    R.bias[0] = b00;   R.bias[1] = b01;
    R.bias[2] = bpre1; R.bias[3] = bpost1;
    R.bias[4] = bpre2; R.bias[5] = bpost2;
    R.bias[6] = bpre3; R.bias[7] = bpost3;
    R.bias[8] = bfin;
    R.rPre = rPre; R.rW01 = rW01;
    R.rWp[0] = rWp1; R.rWp[1] = rWp2; R.rWp[2] = rWp3;
    R.rFin = rFin; R.cbias = cbias;

    prepA_kernel<<<1093, 256, 0, stream>>>(input, histT, keyloc, R);
    scatter_kernel<<<128, 256, 0, stream>>>(histT, keyloc, perm, tileInfo);

    MainP P;
    P.rPre = rPre; P.rW01 = rW01; P.rWp1 = rWp1; P.rWp2 = rWp2; P.rWp3 = rWp3;
    P.rFin = rFin; P.cbias = cbias;
    main_kernel<<<MAXTILE, 1024, 0, stream>>>(input, perm, tileInfo, P, d_out);
}

// Round 12
// 194.728 us; speedup vs baseline: 1.0904x; 1.0904x over previous
//
#include <hip/hip_runtime.h>

#define NB 32768
#define MAXTILE 768
#define ROWS 64
#define NT 4
#define XHS 536            // xh stride in u16: 268 dw ≡ 12 mod 32 → phase-minimal LDS access

typedef short s8v __attribute__((ext_vector_type(8)));   // 8 x bf16 bits (4 VGPR)
typedef short s4v __attribute__((ext_vector_type(4)));
typedef float f4v __attribute__((ext_vector_type(4)));
typedef unsigned short u16;
typedef unsigned short u16x4 __attribute__((ext_vector_type(4)));
typedef unsigned int u32;
typedef unsigned char u8;

__device__ __forceinline__ float bf2f(u16 u) { return __uint_as_float(((u32)u) << 16); }
__device__ __forceinline__ u16 f2bf(float f) {
    u32 x = __float_as_uint(f);
    x += 0x7FFFu + ((x >> 16) & 1u);   // RNE
    return (u16)(x >> 16);
}
__device__ __forceinline__ s8v ld8(const u16* p) { return *reinterpret_cast<const s8v*>(p); }

#define MFMA16(a, b, c) __builtin_amdgcn_mfma_f32_16x16x32_bf16((a), (b), (c), 0, 0, 0)

template <int N> struct IC { static constexpr int v = N; };

// dtype probe, done locally per block (wave 0 ballot -> LDS). bf16=1, f32=0.
__device__ __forceinline__ void detect_flag(const void* input, int tid, int* shflag)
{
    if (tid < 64) {
        u32 w = ((const u32*)input)[tid];
        u32 h0 = w & 0xFFFFu;
        u32 e0 = (h0 >> 7) & 0xFFu;
        bool plaus = (h0 == 0u) || (e0 >= 96u && e0 <= 143u);
        unsigned long long m = __ballot(plaus);
        if (tid == 0) *shflag = (__popcll(m) >= 48) ? 1 : 0;
    }
}

// ---------------------------------------------------------------------------
// dispatch A: blocks [0,128): per-block key histogram -> histT[key][block]
// + keyloc[row] = key | (rank<<8).
// blocks [128,1093): weight repack in fine units (2048 elems) + biases.
// ---------------------------------------------------------------------------
struct RepArgs {
    const void* W01; const void* Wp[3]; const void* pre[4]; const void* fin;
    const void* bias[9];
    u16 *rPre, *rW01, *rWp[3], *rFin, *cbias;
};

__global__ __launch_bounds__(256) void prepA_kernel(const void* __restrict__ inputv,
                                                    int* __restrict__ histT,      // [256][128]
                                                    u16* __restrict__ keyloc,     // [NB]
                                                    RepArgs R)
{
    __shared__ int lcnt[256];
    __shared__ u16 T[2048];
    __shared__ int shmisc;
    int tid = threadIdx.x;
    int b = blockIdx.x;
    detect_flag(inputv, tid, &shmisc);
    __syncthreads();
    int flag = shmisc;

    if (b < 128) {
        lcnt[tid] = 0;
        __syncthreads();
        int row = (b << 8) + tid;
        const u32* in32 = (const u32*)inputv;
        const u16* in16 = (const u16*)inputv;
        int key = 0;
#pragma unroll
        for (int j = 0; j < 4; j++) {
            int base = row * 144 + 128 + j * 4;
            u32 v1, v2, v3;
            if (flag) { v1 = in16[base + 1]; v2 = in16[base + 2]; v3 = in16[base + 3]; }
            else      { v1 = in32[base + 1]; v2 = in32[base + 2]; v3 = in32[base + 3]; }
            int m = v1 ? 1 : (v2 ? 2 : (v3 ? 3 : 0));
            key |= m << (j << 1);
        }
        int loc = atomicAdd(&lcnt[key], 1);
        keyloc[row] = (u16)(key | (loc << 8));
        __syncthreads();
        histT[tid * 128 + b] = lcnt[tid];
        return;
    }

    // ---- repack path: fine units
    int rb = b - 128;
    const void* src; u16* dst; int K, k0, mrow, kq;
    if (rb < 128) {
        int tile = rb >> 2; kq = rb & 3;
        int m = tile >> 3, s = tile & 7;
        src = R.W01; dst = R.rW01 + (m * 8 + s) * 8192; K = 256; k0 = s * 32; mrow = m;
    } else if (rb < 896) {
        int u = rb - 128, mat = u >> 8, r = u & 255;
        int tile = r >> 2; kq = r & 3;
        int m = tile >> 4, s = tile & 15;
        src = R.Wp[mat]; dst = R.rWp[mat] + (m * 16 + s) * 8192; K = 512; k0 = s * 32; mrow = m;
    } else if (rb < 960) {
        int u = rb - 896;
        int tile = u >> 2; kq = u & 3;
        int mat = tile >> 2, m = tile & 3;
        src = R.pre[mat]; dst = R.rPre + (mat * 4 + m) * 8192; K = 32; k0 = 0; mrow = m;
    } else if (rb < 964) {
        int m = rb - 960;   // Wfin [m][256][8] -> [m][s8][lane][8], rows l16>=8 zero
        const u16* s16 = (const u16*)R.fin;
        const float* s32 = (const float*)R.fin;
        u16* d = R.rFin + m * 4096;
        for (int half = 0; half < 2; half++) {
            for (int i = tid; i < 1024; i += 256) {
                int kk = half * 128 + (i >> 3);
                T[i] = flag ? s16[(m * 256 + kk) * 8 + (i & 7)]
                            : f2bf(s32[(m * 256 + kk) * 8 + (i & 7)]);
            }
            __syncthreads();
            for (int i = tid; i < 2048; i += 256) {
                int s = (half << 2) + (i >> 9), lane = (i >> 3) & 63, j = i & 7;
                int q = lane >> 4, l16 = lane & 15;
                int k = s * 32 + q * 8 + j;
                d[s * 512 + lane * 8 + j] = (l16 < 8) ? T[(k - half * 128) * 8 + l16] : (u16)0;
            }
            __syncthreads();
        }
        return;
    } else {
        const int sz[9] = {1024,1024,1024,1024,1024,1024,1024,1024,32};
        const int of[9] = {0,1024,2048,3072,4096,5120,6144,7168,8192};
        for (int i = tid; i < 8224; i += 256) {
            int t = i, e = 0;
            while (t >= sz[e]) { t -= sz[e]; e++; }
            R.cbias[of[e] + t] = flag ? ((const u16*)R.bias[e])[t]
                                      : f2bf(((const float*)R.bias[e])[t]);
        }
        return;
    }
    const u16* s16 = (const u16*)src;
    const float* s32 = (const float*)src;
    for (int i = tid; i < 2048; i += 256) {
        int kk = i >> 8, n = i & 255;
        int srcIdx = (mrow * K + k0 + kq * 8 + kk) * 256 + n;
        T[i] = flag ? s16[srcIdx] : f2bf(s32[srcIdx]);
    }
    __syncthreads();
    for (int i = tid; i < 2048; i += 256) {
        int mt = i >> 7, r = i & 127, l15 = r >> 3, j = i & 7;
        dst[mt * 512 + kq * 128 + r] = T[j * 256 + mt * 16 + l15];
    }
}

// ---------------------------------------------------------------------------
// dispatch B: 128 blocks. Redundant per-block scan (no spin) -> per-key base;
// scatter perm. Block 0 emits tile table + publishes real tile count.
// ---------------------------------------------------------------------------
__global__ __launch_bounds__(256) void scatter_kernel(const int* __restrict__ histT,
                                                      const u16* __restrict__ keyloc,
                                                      int* __restrict__ perm,
                                                      int4* __restrict__ tileInfo,
                                                      int* __restrict__ tcount)
{
    __shared__ int lcnt[256];
    __shared__ int sBase[256];
    int tid = threadIdx.x;
    int b = blockIdx.x;

    const int4* hrow = (const int4*)(histT + tid * 128);
    int tot = 0, before = 0;
#pragma unroll
    for (int j = 0; j < 32; j++) {
        int4 h = hrow[j];
        int i4 = j << 2;
        tot += h.x + h.y + h.z + h.w;
        if (i4 + 0 < b) before += h.x;
        if (i4 + 1 < b) before += h.y;
        if (i4 + 2 < b) before += h.z;
        if (i4 + 3 < b) before += h.w;
    }
    lcnt[tid] = tot;
    __syncthreads();
    for (int off = 1; off < 256; off <<= 1) {
        int v = (tid >= off) ? lcnt[tid - off] : 0;
        __syncthreads();
        lcnt[tid] += v;
        __syncthreads();
    }
    int gbase = lcnt[tid] - tot;
    sBase[tid] = gbase + before;
    __syncthreads();

    if (b == 0) {
        int tiles = (tot + ROWS - 1) / ROWS;
        lcnt[tid] = tiles;
        __syncthreads();
        for (int off = 1; off < 256; off <<= 1) {
            int v = (tid >= off) ? lcnt[tid - off] : 0;
            __syncthreads();
            lcnt[tid] += v;
            __syncthreads();
        }
        int tbase = lcnt[tid] - tiles;
        int ttot = lcnt[255];
        if (tid == 0) tcount[0] = ttot;
        for (int t = 0; t < tiles; t++) {
            int rem = tot - t * ROWS;
            tileInfo[tbase + t] = make_int4(tid, gbase + t * ROWS, rem > ROWS ? ROWS : rem, 0);
        }
        for (int i = ttot + tid; i < MAXTILE; i += 256)
            tileInfo[i] = make_int4(0, 0, 0, 0);
    }

    // ---- scatter perm
    int row = (b << 8) + tid;
    u32 kl = keyloc[row];
    int key = kl & 255, loc = kl >> 8;
    perm[sBase[key] + loc] = row;
}

// ---------------------------------------------------------------------------
// main: one block = 64 rows through the whole net (T-formulation).
// 8 waves; wave w: m-tiles {2w,2w+1} x 4 n-tiles. Fused K gemm, depth-4
// prefetch issued before the barrier. BALANCED XCD-contiguous partitioning:
// XCD x = b&7 owns real tiles [x*ceil(T/8), ...) — contiguous keys fix the
// high module bits, so the per-XCD weight working set (~2.2MB) fits its L2.
// ---------------------------------------------------------------------------
struct MainP { const u16 *rPre, *rW01, *rWp1, *rWp2, *rWp3, *rFin, *cbias; };

__global__ __launch_bounds__(512, 4) void main_kernel(
    const void* __restrict__ inRaw,
    const int* __restrict__ perm, const int4* __restrict__ tileInfo,
    const int* __restrict__ tcount,
    MainP P, void* __restrict__ outp)
{
    __shared__ __align__(16) u16 xh[ROWS * XHS];
    __shared__ int rowids[ROWS];
    __shared__ int shflag;

    int tid = threadIdx.x;
    int lane = tid & 63, w = tid >> 6, quad = lane >> 4, l16 = lane & 15;

    int T = tcount[0];
    int tpx = (T + 7) >> 3;
    int x = blockIdx.x & 7, i = blockIdx.x >> 3;
    if (i >= tpx) return;
    int t = x * tpx + i;
    if (t >= T) return;
    int4 ti = tileInfo[t];
    int key = ti.x, ppos = ti.y, cntIn = ti.z;
    if (cntIn <= 0) return;

    detect_flag(inRaw, tid, &shflag);
    if (tid < ROWS) {
        int g = tid < cntIn ? tid : cntIn - 1;   // clamp partial tile (dups benign)
        rowids[tid] = perm[ppos + g];
    }
    __syncthreads();
    int flag = shflag;
    int rows_[NT];
#pragma unroll
    for (int nt = 0; nt < NT; nt++) rows_[nt] = rowids[nt * 16 + l16];

    const u16* in16 = (const u16*)inRaw;
    const float* in32 = (const float*)inRaw;
    int mt0 = w << 1, mt1 = mt0 + 1;

    f4v acc0[NT], acc1[NT];

    // N-slice fused GEMM: depth-4 prefetch issued BEFORE the hp-visibility
    // barrier (A-frags don't depend on xh).
    auto gemm_run = [&](auto nc, const u16* Ab, int ks0) {
        constexpr int N = decltype(nc)::v;
        constexpr int D = 4;
        const u16* base0 = Ab + mt0 * 512 + lane * 8;
        const u16* base1 = Ab + mt1 * 512 + lane * 8;
        s8v A0[D], A1[D];
#pragma unroll
        for (int d = 0; d < D && d < N; d++) {
            A0[d] = ld8(base0 + d * 8192);
            A1[d] = ld8(base1 + d * 8192);
        }
        __syncthreads();                     // hp/hq now visible; prefetch in flight
#pragma unroll
        for (int s = 0; s < N; s++) {
            s8v c0 = A0[s % D], c1 = A1[s % D];
            if (s + D < N) {
                A0[s % D] = ld8(base0 + (s + D) * 8192);
                A1[s % D] = ld8(base1 + (s + D) * 8192);
            }
#pragma unroll
            for (int nt = 0; nt < NT; nt++) {
                s8v B = ld8(&xh[(nt * 16 + l16) * XHS + (ks0 + s) * 32 + quad * 8]);
                acc0[nt] = MFMA16(c0, B, acc0[nt]);
                acc1[nt] = MFMA16(c1, B, acc1[nt]);
            }
        }
    };

    for (int node = 0; node < 4; node++) {
        int m = (key >> (node << 1)) & 3;

        // ---- feats B-frags: direct gather (128B contiguous per row per node)
        s8v fb[NT];
#pragma unroll
        for (int nt = 0; nt < NT; nt++) {
            int off = rows_[nt] * 144 + (node << 5) + (quad << 3);
            if (flag) fb[nt] = ld8(in16 + off);
            else {
                f4v f0 = *(const f4v*)(in32 + off);
                f4v f1 = *(const f4v*)(in32 + off + 4);
                s8v r;
#pragma unroll
                for (int j = 0; j < 4; j++) { r[j] = (short)f2bf(f0[j]); r[4 + j] = (short)f2bf(f1[j]); }
                fb[nt] = r;
            }
        }

        // ---- hp^T = relu(Wpre^T @ feats^T + bpre) -> xh[.,256..511]
        const u16* preB = P.rPre + ((node << 2) + m) * 8192;
#pragma unroll
        for (int ci = 0; ci < 2; ci++) {
            int mt = mt0 + ci;
            s8v a = ld8(preB + mt * 512 + lane * 8);
            u16x4 bv = *(const u16x4*)(P.cbias + node * 2048 + m * 256 + mt * 16 + quad * 4);
            f4v bias;
#pragma unroll
            for (int r = 0; r < 4; r++) bias[r] = bf2f(bv[r]);
#pragma unroll
            for (int nt = 0; nt < NT; nt++) {
                f4v c = MFMA16(a, fb[nt], bias);
                s4v p;
#pragma unroll
                for (int r = 0; r < 4; r++) { float v = c[r] > 0.f ? c[r] : 0.f; p[r] = (short)f2bf(v); }
                *(s4v*)&xh[(nt * 16 + l16) * XHS + 256 + mt * 16 + quad * 4] = p;
            }
        }

        // ---- acc init with bpost
        {
            u16x4 b0 = *(const u16x4*)(P.cbias + node * 2048 + 1024 + m * 256 + mt0 * 16 + quad * 4);
            u16x4 b1 = *(const u16x4*)(P.cbias + node * 2048 + 1024 + m * 256 + mt1 * 16 + quad * 4);
            f4v f0, f1;
#pragma unroll
            for (int r = 0; r < 4; r++) { f0[r] = bf2f(b0[r]); f1[r] = bf2f(b1[r]); }
#pragma unroll
            for (int nt = 0; nt < NT; nt++) { acc0[nt] = f0; acc1[nt] = f1; }
        }

        // ---- fused K-loop (barrier inside gemm_run, after prefetch issue)
        if (node == 0) gemm_run(IC<8>{},  P.rW01 + m * 8 * 8192, 8);
        else {
            const u16* WB = (node == 1 ? P.rWp1 : (node == 2 ? P.rWp2 : P.rWp3)) + m * 16 * 8192;
            gemm_run(IC<16>{}, WB, 0);
        }
        __syncthreads();                       // all xh reads of this node done

        // ---- relu + write hq^T -> xh[.,0..255]
#pragma unroll
        for (int ci = 0; ci < 2; ci++) {
            int mt = mt0 + ci;
#pragma unroll
            for (int nt = 0; nt < NT; nt++) {
                f4v a = ci ? acc1[nt] : acc0[nt];
                s4v p;
#pragma unroll
                for (int r = 0; r < 4; r++) { float v = a[r] > 0.f ? a[r] : 0.f; p[r] = (short)f2bf(v); }
                *(s4v*)&xh[(nt * 16 + l16) * XHS + mt * 16 + quad * 4] = p;
            }
        }
    }
    __syncthreads();

    // ---- final: out^T = Wfin^T @ x3^T + bfin (waves 0..NT-1 cover all rows)
    if (w < NT) {
        int m3 = (key >> 6) & 3;
        f4v c;
#pragma unroll
        for (int r = 0; r < 4; r++)
            c[r] = (quad < 2) ? bf2f(P.cbias[8192 + m3 * 8 + quad * 4 + r]) : 0.f;
#pragma unroll
        for (int s = 0; s < 8; s++) {
            s8v A = ld8(P.rFin + m3 * 4096 + s * 512 + lane * 8);
            s8v B = ld8(&xh[(w * 16 + l16) * XHS + s * 32 + quad * 8]);
            c = MFMA16(A, B, c);
        }
        int bidx = w * 16 + l16;
        if (quad < 2 && bidx < cntIn) {
            int row = rowids[bidx];
            if (flag) {
                s4v p;
#pragma unroll
                for (int r = 0; r < 4; r++) p[r] = (short)f2bf(c[r]);
                *(s4v*)((u16*)outp + row * 8 + quad * 4) = p;
            } else {
                *(f4v*)((float*)outp + row * 8 + quad * 4) = c;
            }
        }
    }
}

// ---------------------------------------------------------------------------
extern "C" void kernel_launch(void* const* d_in, const int* in_sizes, int n_in,
                              void* d_out, int out_size, void* d_ws, size_t ws_size,
                              hipStream_t stream)
{
    (void)in_sizes; (void)n_in; (void)out_size;
    const void* input  = d_in[0];
    const void* W00    = d_in[1];
    const void* b00    = d_in[2];
    const void* W01    = d_in[3];
    const void* b01    = d_in[4];
    const void* Wpre1  = d_in[5];
    const void* bpre1  = d_in[6];
    const void* Wpost1 = d_in[7];
    const void* bpost1 = d_in[8];
    const void* Wpre2  = d_in[9];
    const void* bpre2  = d_in[10];
    const void* Wpost2 = d_in[11];
    const void* bpost2 = d_in[12];
    const void* Wpre3  = d_in[13];
    const void* bpre3  = d_in[14];
    const void* Wpost3 = d_in[15];
    const void* bpost3 = d_in[16];
    const void* Wfin   = d_in[17];
    const void* bfin   = d_in[18];

    char* base = (char*)d_ws;
    size_t off = 0;
    auto alloc = [&](size_t bytes) -> char* {
        char* p = base + off;
        off += (bytes + 255) & ~(size_t)255;
        return p;
    };
    int*  histT     = (int*)alloc(256 * 128 * 4);     // [key][block]
    u16*  keyloc    = (u16*)alloc(NB * 2);
    int4* tileInfo  = (int4*)alloc(MAXTILE * 16);
    int*  perm      = (int*)alloc((size_t)NB * 4);
    int*  tcount    = (int*)alloc(4);
    u16*  cbias    = (u16*)alloc(8224 * 2);
    u16*  rPre     = (u16*)alloc(131072 * 2);
    u16*  rW01     = (u16*)alloc(262144 * 2);
    u16*  rWp1     = (u16*)alloc(524288 * 2);
    u16*  rWp2     = (u16*)alloc(524288 * 2);
    u16*  rWp3     = (u16*)alloc(524288 * 2);
    u16*  rFin     = (u16*)alloc(16384 * 2);
    if (off > ws_size) return;

    RepArgs R;
    R.W01 = W01; R.Wp[0] = Wpost1; R.Wp[1] = Wpost2; R.Wp[2] = Wpost3;
    R.pre[0] = W00; R.pre[1] = Wpre1; R.pre[2] = Wpre2; R.pre[3] = Wpre3;
    R.fin = Wfin;
    R.bias[0] = b00;   R.bias[1] = b01;
    R.bias[2] = bpre1; R.bias[3] = bpost1;
    R.bias[4] = bpre2; R.bias[5] = bpost2;
    R.bias[6] = bpre3; R.bias[7] = bpost3;
    R.bias[8] = bfin;
    R.rPre = rPre; R.rW01 = rW01;
    R.rWp[0] = rWp1; R.rWp[1] = rWp2; R.rWp[2] = rWp3;
    R.rFin = rFin; R.cbias = cbias;

    prepA_kernel<<<1093, 256, 0, stream>>>(input, histT, keyloc, R);
    scatter_kernel<<<128, 256, 0, stream>>>(histT, keyloc, perm, tileInfo, tcount);

    MainP P;
    P.rPre = rPre; P.rW01 = rW01; P.rWp1 = rWp1; P.rWp2 = rWp2; P.rWp3 = rWp3;
    P.rFin = rFin; P.cbias = cbias;
    main_kernel<<<MAXTILE, 512, 0, stream>>>(input, perm, tileInfo, tcount, P, d_out);
}